// Round 15
// baseline (377.286 us; speedup 1.0000x reference)
//
#include <hip/hip_runtime.h>
#include <hip/hip_bf16.h>
#include <math.h>

// MultiBoxLoss: B=64, P=16800, G=32, C=2. TWO-kernel pipeline:
// k_gt : per-gt best-prior argmax + per-prior threshold bitmask -> keys+wmask;
//        packs gt table; resets done counters.
// k_ms : per-prior conf+losses from bitmask (g-loop deleted, r12 ablation);
//        per-batch LAST block (doneA counter) runs that batch's exact top-k
//        (4-way bisection over bc re-read from L2); global done2 last block
//        folds 64 rows -> 3 scalars. No third launch, select overlaps match.

#define RCP(x) __builtin_amdgcn_rcpf(x)
typedef unsigned long long u64;

constexpr int GN = 32;
constexpr int PACKF = 576;
constexpr int NW64A = 264;   // mask words per (batch, chunk)

__device__ __forceinline__ float sl1(float x) {
    float a = fabsf(x);
    return a < 1.f ? 0.5f * a * a : a - 0.5f;
}

// ---- k_gt: argmax + threshold bitmask + gt pack (r13-proven) ----
constexpr int GPB = 4;       // gts per chunk
constexpr int GNT = 1024;
__global__ __launch_bounds__(GNT)
void k_gt(const float4* __restrict__ priors, const float* __restrict__ targets,
          u64* __restrict__ keys, float* __restrict__ pack, u64* __restrict__ wmask,
          int* __restrict__ doneA, int* __restrict__ done2, int P, int G, int NCH) {
    const int b = blockIdx.y, cx = blockIdx.x, g0 = cx * GPB, tid = threadIdx.x;
    const int lane = tid & 63, w = tid >> 6;
    if (cx == 0 && tid == 0) doneA[b] = 0;
    if (cx == 0 && b == 0 && tid == 1) *done2 = 0;
    __shared__ float4 s_box[GPB];
    __shared__ float  s_at[GPB];
    __shared__ u64 s_wk[GNT / 64][GPB];
    if (tid < GPB) {
        const float* t = targets + ((size_t)b * G + g0 + tid) * 15;
        float4 v = make_float4(t[0], t[1], t[2], t[3]);
        float at = (v.z - v.x) * (v.w - v.y);
        s_box[tid] = v;
        s_at[tid] = at;
        float* pkw = pack + (size_t)b * PACKF;
        ((float4*)pkw)[g0 + tid] = v;
        pkw[128 + g0 + tid] = 0.35f * at;
        pkw[160 + g0 + tid] = at;
        pkw[192 + g0 + tid] = t[14];
    }
    {
        int q = tid - GPB;
        if (q >= 0 && q < GPB * 10) {
            int gg = g0 + q / 10, j = q % 10;
            pack[(size_t)b * PACKF + 224 + gg * 10 + j] =
                targets[((size_t)b * G + gg) * 15 + 4 + j];
        }
    }
    __syncthreads();
    float4 tb0 = s_box[0], tb1 = s_box[1], tb2 = s_box[2], tb3 = s_box[3];
    float at0 = s_at[0], at1 = s_at[1], at2 = s_at[2], at3 = s_at[3];
    float c0 = 0.35f * at0, c1 = 0.35f * at1, c2 = 0.35f * at2, c3 = 0.35f * at3;

    u64* __restrict__ wm = wmask + ((size_t)b * NCH + cx) * NW64A;

    float bv[GPB]; int bp[GPB];
    #pragma unroll
    for (int j = 0; j < GPB; ++j) { bv[j] = -1.f; bp[j] = 0; }

    for (int p = tid; p < P; p += GNT) {     // ascending p: '>' keeps smallest p
        float4 pr = priors[p];
        float hx = pr.z * 0.5f, hy = pr.w * 0.5f;
        float px0 = pr.x - hx, py0 = pr.y - hy;
        float px1 = pr.x + hx, py1 = pr.y + hy;
        float ap = (px1 - px0) * (py1 - py0);
        float ap35 = 0.35f * ap;
        bool pa = false;
        #pragma unroll
        for (int j = 0; j < GPB; ++j) {
            float4 tb = j == 0 ? tb0 : (j == 1 ? tb1 : (j == 2 ? tb2 : tb3));
            float at = j == 0 ? at0 : (j == 1 ? at1 : (j == 2 ? at2 : at3));
            float cj = j == 0 ? c0 : (j == 1 ? c1 : (j == 2 ? c2 : c3));
            float lx = fmaxf(tb.x, px0), ly = fmaxf(tb.y, py0);
            float rx = fminf(tb.z, px1), ry = fminf(tb.w, py1);
            float iw = fmaxf(rx - lx, 0.f), ih = fmaxf(ry - ly, 0.f);
            float inter = iw * ih;
            pa = pa || (fmaf(1.35f, inter, -cj) >= ap35);   // iou >= 0.35
            float iou = inter * RCP(at + ap - inter);
            if (iou > bv[j]) { bv[j] = iou; bp[j] = p; }
        }
        u64 bal = __ballot(pa);
        if (lane == 0) wm[p >> 6] = bal;
    }
    #pragma unroll
    for (int j = 0; j < GPB; ++j) {
        u64 key = ((u64)__float_as_uint(bv[j]) << 32) | ~(unsigned)bp[j];
        #pragma unroll
        for (int o = 32; o > 0; o >>= 1) {
            u64 t = __shfl_down(key, o, 64);
            if (t > key) key = t;
        }
        if (lane == 0) s_wk[w][j] = key;
    }
    __syncthreads();
    if (tid < GPB) {
        u64 m = 0ull;
        #pragma unroll
        for (int q = 0; q < GNT / 64; ++q) { u64 t = s_wk[q][tid]; if (t > m) m = t; }
        keys[b * G + g0 + tid] = m;
    }
}

// ---- k_ms: match (no g-loop) + per-batch select tail + global fold ----
__global__ __launch_bounds__(256)
void k_ms(const float2* __restrict__ cls, const float4* __restrict__ loc,
          const float* __restrict__ lmd, const float4* __restrict__ priors,
          const float* __restrict__ pack, const u64* __restrict__ keys,
          const u64* __restrict__ wmask,
          float* __restrict__ bc, float* __restrict__ part, float* __restrict__ part2,
          float* __restrict__ out, int* __restrict__ doneA, int* __restrict__ done2,
          int P, int NB, int NCH, int B) {
    const int b = blockIdx.y, bx = blockIdx.x, tid = threadIdx.x;
    const int lane = tid & 63, w = tid >> 6;
    const float* __restrict__ pk = pack + (size_t)b * PACKF;
    const float4* __restrict__ gbox = (const float4*)pk;
    const float* __restrict__ garea = pk + 160;
    const float* __restrict__ glab = pk + 192;
    const float* __restrict__ glm  = pk + 224;

    __shared__ int s_fg[256];
    __shared__ int s_fv[256];
    __shared__ unsigned s_vm;
    __shared__ float s_red[4][8];
    __shared__ float s_fld[5];
    __shared__ u64   s_cw[4];
    __shared__ u64   s_ct;
    __shared__ float s_rf[4][2];
    __shared__ int   s_last, s_last2;

    s_fg[tid] = -1; s_fv[tid] = 0;
    __syncthreads();
    if (tid < GN) {                                   // forced-match scatter
        u64 key = keys[b * GN + tid];
        unsigned bp = ~(unsigned)key;
        bool val = __uint_as_float((unsigned)(key >> 32)) >= 0.2f;
        u64 bal = __ballot(val);
        if (tid == 0) s_vm = (unsigned)bal;
        int local = (int)bp - bx * 256;
        if (local >= 0 && local < 256) {
            atomicMax(&s_fg[local], tid);
            if (val) atomicOr(&s_fv[local], 1);
        }
    }

    int p = bx * 256 + tid;
    const bool act = p < P;
    float2 c = act ? cls[(size_t)b * P + p] : make_float2(0.f, 0.f);

    // threshold: OR chunk masks for this wave's 64-prior word (uniform loads)
    const int word = bx * 4 + w;
    u64 m = 0ull;
    #pragma unroll
    for (int ch = 0; ch < 8; ++ch)
        m |= wmask[((size_t)b * NCH + ch) * NW64A + word];
    __syncthreads();                                  // covers scatter
    const bool av = s_vm != 0u;

    bool thr = act && ((m >> lane) & 1ull);
    int fidx = s_fg[tid];
    bool fv = s_fv[tid] != 0;
    bool pos = act && av && (fv || thr);

    float lse = 0.f, d = 0.f;
    if (act) {
        d = c.y - c.x;
        float m0 = fmaxf(d, 0.f);
        lse = m0 + __logf(__expf(-m0) + __expf(d - m0));   // logz - c.x >= 0
        bc[(size_t)b * P + p] = pos ? 0.f : lse;
    }

    float a_ll = 0.f, a_lm = 0.f, a_lcp = 0.f;
    bool posl = false;
    if (pos) {                                        // rare path
        a_lcp = lse - d;
        float4 pr = priors[p];
        float hx = pr.z * 0.5f, hy = pr.w * 0.5f;
        float px0 = pr.x - hx, py0 = pr.y - hy;
        float px1 = pr.x + hx, py1 = pr.y + hy;
        float ap = (px1 - px0) * (py1 - py0);
        int bti2 = fidx;
        if (fidx < 0) {                               // full first-g argmax
            float btv = -1.f;
            #pragma unroll 1
            for (int g = 0; g < GN; ++g) {
                float4 tb = gbox[g];
                float lx = fmaxf(tb.x, px0), ly = fmaxf(tb.y, py0);
                float rx = fminf(tb.z, px1), ry = fminf(tb.w, py1);
                float iw = fmaxf(rx - lx, 0.f), ih = fmaxf(ry - ly, 0.f);
                float inter = iw * ih;
                float iou = inter * RCP(garea[g] + ap - inter);
                if (iou > btv) { btv = iou; bti2 = g; }
            }
        }
        float4 tb = gbox[bti2];
        float rw = RCP(pr.z), rh = RCP(pr.w);
        float e0 = ((tb.x + tb.z) * 0.5f - pr.x) * rw * 10.f;
        float e1 = ((tb.y + tb.w) * 0.5f - pr.y) * rh * 10.f;
        float e2 = __logf((tb.z - tb.x) * rw) * 5.f;
        float e3 = __logf((tb.w - tb.y) * rh) * 5.f;
        float4 ld = loc[(size_t)b * P + p];
        a_ll = sl1(ld.x - e0) + sl1(ld.y - e1) + sl1(ld.z - e2) + sl1(ld.w - e3);
        if (glab[bti2] > 0.f) {
            posl = true;
            const float* lp = lmd + ((size_t)b * P + p) * 10;
            #pragma unroll
            for (int q = 0; q < 5; ++q) {
                float gx = (glm[bti2 * 10 + 2 * q]     - pr.x) * rw * 10.f;
                float gy = (glm[bti2 * 10 + 2 * q + 1] - pr.y) * rh * 10.f;
                a_lm += sl1(lp[2 * q] - gx) + sl1(lp[2 * q + 1] - gy);
            }
        }
    }

    u64 bpos = __ballot(pos);
    int npw  = __popcll(bpos);
    int np1w = __popcll(__ballot(posl));
    if (bpos) {
        #pragma unroll
        for (int o = 32; o > 0; o >>= 1) {
            a_ll  += __shfl_down(a_ll,  o, 64);
            a_lm  += __shfl_down(a_lm,  o, 64);
            a_lcp += __shfl_down(a_lcp, o, 64);
        }
    }
    if (lane == 0) {
        s_red[w][0] = a_ll; s_red[w][1] = a_lm; s_red[w][2] = a_lcp;
        s_red[w][3] = (float)npw; s_red[w][4] = (float)np1w;
    }
    __syncthreads();
    if (tid == 0) {
        float* pp = part + ((size_t)b * NB + bx) * 8;
        #pragma unroll
        for (int j = 0; j < 5; ++j)
            pp[j] = s_red[0][j] + s_red[1][j] + s_red[2][j] + s_red[3][j];
        __threadfence();
        int old = atomicAdd(&doneA[b], 1);
        s_last = (old == NB - 1) ? 1 : 0;
    }
    __syncthreads();
    if (!s_last) return;
    __threadfence();                                  // acquire: all bc/part visible

    // ============ per-batch select tail (last block of batch b) ============
    if (w < 4) {                                      // field sums over 66 rows
        for (int j = w; j < 5; j += 4) {
            float s = 0.f;
            for (int r = lane; r < NB; r += 64) s += part[((size_t)b * NB + r) * 8 + j];
            #pragma unroll
            for (int o = 32; o > 0; o >>= 1) s += __shfl_down(s, o, 64);
            if (lane == 0) s_fld[j] = s;
        }
    }
    __syncthreads();
    const float t_ll = s_fld[0], t_lm = s_fld[1], t_lcp = s_fld[2];
    const float t_np = s_fld[3], t_np1 = s_fld[4];
    int k = (int)(t_np + 0.5f) * 7;
    if (k > P - 1) k = P - 1;

    float topk = 0.f;
    const float* __restrict__ vb = bc + (size_t)b * P;
    if (k > 0) {
        unsigned lo = 0u, hi = 0x7f800000u;           // finite non-negative values
        while (lo < hi) {                             // ~8 rounds (4-way)
            unsigned span = hi - lo;
            unsigned m1 = lo + ((span + 3) >> 2);
            unsigned m2 = lo + ((span + 1) >> 1);
            unsigned m3 = hi - (span >> 2);
            int c1 = 0, c2 = 0, c3 = 0;
            for (int i = tid; i < P; i += 256) {      // L2-hot re-read
                unsigned u = __float_as_uint(vb[i]);
                c1 += u >= m1 ? 1 : 0;
                c2 += u >= m2 ? 1 : 0;
                c3 += u >= m3 ? 1 : 0;
            }
            u64 pkk = (u64)c1 | ((u64)c2 << 20) | ((u64)c3 << 40);
            #pragma unroll
            for (int o = 32; o > 0; o >>= 1) pkk += __shfl_down(pkk, o, 64);
            if (lane == 0) s_cw[w] = pkk;
            __syncthreads();
            if (tid == 0) s_ct = s_cw[0] + s_cw[1] + s_cw[2] + s_cw[3];
            __syncthreads();
            u64 t = s_ct;
            int C1 = (int)(t & 0xFFFFFu);
            int C2 = (int)((t >> 20) & 0xFFFFFu);
            int C3 = (int)((t >> 40) & 0xFFFFFu);
            if      (C3 >= k) lo = m3;
            else if (C2 >= k) { lo = m2; hi = m3 - 1; }
            else if (C1 >= k) { lo = m1; hi = m2 - 1; }
            else hi = m1 - 1;
        }
        float fT = __uint_as_float(lo);               // exact k-th largest
        float s = 0.f, cf = 0.f;
        for (int i = tid; i < P; i += 256) {
            unsigned u = __float_as_uint(vb[i]);
            if (u > lo) { s += __uint_as_float(u); cf += 1.f; }
        }
        #pragma unroll
        for (int o = 32; o > 0; o >>= 1) {
            s  += __shfl_down(s, o, 64);
            cf += __shfl_down(cf, o, 64);
        }
        if (lane == 0) { s_rf[w][0] = s; s_rf[w][1] = cf; }
        __syncthreads();
        if (tid == 0) {
            float ts = s_rf[0][0] + s_rf[1][0] + s_rf[2][0] + s_rf[3][0];
            float tc = s_rf[0][1] + s_rf[1][1] + s_rf[2][1] + s_rf[3][1];
            topk = ts + ((float)k - tc) * fT;         // ties add (k-cnt)*T
        }
    }
    if (tid == 0) {
        float* pp = part2 + b * 8;
        pp[0] = t_ll; pp[1] = t_lm; pp[2] = t_lcp;
        pp[3] = topk; pp[4] = t_np; pp[5] = t_np1;
        __threadfence();
        int old = atomicAdd(done2, 1);
        s_last2 = (old == B - 1) ? 1 : 0;
    }
    __syncthreads();
    if (s_last2 && w == 0) {                          // last batch folds all rows
        __threadfence();
        volatile float* vp = part2;
        float ll = 0.f, lm = 0.f, lc = 0.f, tk = 0.f, np = 0.f, np1 = 0.f;
        for (int bb = lane; bb < B; bb += 64) {
            ll  += vp[bb * 8 + 0];
            lm  += vp[bb * 8 + 1];
            lc  += vp[bb * 8 + 2];
            tk  += vp[bb * 8 + 3];
            np  += vp[bb * 8 + 4];
            np1 += vp[bb * 8 + 5];
        }
        #pragma unroll
        for (int o = 32; o > 0; o >>= 1) {
            ll  += __shfl_down(ll,  o, 64);
            lm  += __shfl_down(lm,  o, 64);
            lc  += __shfl_down(lc,  o, 64);
            tk  += __shfl_down(tk,  o, 64);
            np  += __shfl_down(np,  o, 64);
            np1 += __shfl_down(np1, o, 64);
        }
        if (lane == 0) {
            float N = fmaxf(np, 1.f), N1 = fmaxf(np1, 1.f);
            out[0] = ll / N;
            out[1] = (lc + tk) / N;
            out[2] = lm / N1;
        }
    }
}

extern "C" void kernel_launch(void* const* d_in, const int* in_sizes, int n_in,
                              void* d_out, int out_size, void* d_ws, size_t ws_size,
                              hipStream_t stream) {
    const float2* cls    = (const float2*)d_in[0];
    const float4* loc    = (const float4*)d_in[1];
    const float* lmd     = (const float*)d_in[2];
    const float4* priors = (const float4*)d_in[3];
    const float* targets = (const float*)d_in[4];
    int P = in_sizes[3] / 4;            // 16800
    int B = (in_sizes[1] / 4) / P;      // 64
    int G = in_sizes[4] / (15 * B);     // 32
    int NB = (P + 255) / 256;           // 66
    int NCH = (G + GPB - 1) / GPB;      // 8 chunks

    size_t off = 0;
    u64* keys    = (u64*)d_ws;                     off += (size_t)B * G * 8;
    u64* wmask   = (u64*)((char*)d_ws + off);      off += (size_t)B * NCH * NW64A * 8;
    float* pack  = (float*)((char*)d_ws + off);    off += (size_t)B * PACKF * 4;
    float* part  = (float*)((char*)d_ws + off);    off += (size_t)B * NB * 8 * 4;
    float* part2 = (float*)((char*)d_ws + off);    off += (size_t)B * 8 * 4;
    int* doneA   = (int*)((char*)d_ws + off);      off += (size_t)B * 4;
    int* done2   = (int*)((char*)d_ws + off);      off += 256;
    off = (off + 255) & ~(size_t)255;
    float* bc    = (float*)((char*)d_ws + off);

    dim3 ggt(NCH, B);
    k_gt<<<ggt, GNT, 0, stream>>>(priors, targets, keys, pack, wmask,
                                  doneA, done2, P, G, NCH);
    dim3 gm(NB, B);
    k_ms<<<gm, 256, 0, stream>>>(cls, loc, lmd, priors, pack, keys, wmask,
                                 bc, part, part2, (float*)d_out, doneA, done2,
                                 P, NB, NCH, B);
}

// Round 16
// 178.532 us; speedup vs baseline: 2.1133x; 2.1133x over previous
//
#include <hip/hip_runtime.h>
#include <hip/hip_bf16.h>
#include <math.h>

// MultiBoxLoss: B=64, P=16800, G=32, C=2. TWO-dispatch pipeline:
// k_gt  (8x64 blocks, 1024 thr): per-gt best-prior argmax + per-prior
//        threshold bitmask -> keys + wmask; packs gt table; resets done.
// k_sel (64 blocks, 1024 thr, 1 per batch): forced-match scatter into LDS
//        table; per-prior conf+losses with conf-loss bits register-resident;
//        exact top-k via 4-way bisection; done-counter last-block fold.
//        No bc global round-trip; device fences only in 64 blocks.

#define RCP(x) __builtin_amdgcn_rcpf(x)
typedef unsigned long long u64;

constexpr int GN = 32;
constexpr int PACKF = 576;
constexpr int NW64A = 264;   // mask words per (batch, chunk)

__device__ __forceinline__ float sl1(float x) {
    float a = fabsf(x);
    return a < 1.f ? 0.5f * a * a : a - 0.5f;
}

// ---- k_gt: argmax + threshold bitmask + gt pack (r13-proven) ----
constexpr int GPB = 4;       // gts per chunk
constexpr int GNT = 1024;
__global__ __launch_bounds__(GNT)
void k_gt(const float4* __restrict__ priors, const float* __restrict__ targets,
          u64* __restrict__ keys, float* __restrict__ pack, u64* __restrict__ wmask,
          int* __restrict__ done, int P, int G, int NCH) {
    const int b = blockIdx.y, cx = blockIdx.x, g0 = cx * GPB, tid = threadIdx.x;
    const int lane = tid & 63, w = tid >> 6;
    if (cx == 0 && b == 0 && tid == 0) *done = 0;
    __shared__ float4 s_box[GPB];
    __shared__ float  s_at[GPB];
    __shared__ u64 s_wk[GNT / 64][GPB];
    if (tid < GPB) {
        const float* t = targets + ((size_t)b * G + g0 + tid) * 15;
        float4 v = make_float4(t[0], t[1], t[2], t[3]);
        float at = (v.z - v.x) * (v.w - v.y);
        s_box[tid] = v;
        s_at[tid] = at;
        float* pkw = pack + (size_t)b * PACKF;
        ((float4*)pkw)[g0 + tid] = v;
        pkw[128 + g0 + tid] = 0.35f * at;
        pkw[160 + g0 + tid] = at;
        pkw[192 + g0 + tid] = t[14];
    }
    {
        int q = tid - GPB;
        if (q >= 0 && q < GPB * 10) {
            int gg = g0 + q / 10, j = q % 10;
            pack[(size_t)b * PACKF + 224 + gg * 10 + j] =
                targets[((size_t)b * G + gg) * 15 + 4 + j];
        }
    }
    __syncthreads();
    float4 tb0 = s_box[0], tb1 = s_box[1], tb2 = s_box[2], tb3 = s_box[3];
    float at0 = s_at[0], at1 = s_at[1], at2 = s_at[2], at3 = s_at[3];
    float c0 = 0.35f * at0, c1 = 0.35f * at1, c2 = 0.35f * at2, c3 = 0.35f * at3;

    u64* __restrict__ wm = wmask + ((size_t)b * NCH + cx) * NW64A;

    float bv[GPB]; int bp[GPB];
    #pragma unroll
    for (int j = 0; j < GPB; ++j) { bv[j] = -1.f; bp[j] = 0; }

    for (int p = tid; p < P; p += GNT) {     // ascending p: '>' keeps smallest p
        float4 pr = priors[p];
        float hx = pr.z * 0.5f, hy = pr.w * 0.5f;
        float px0 = pr.x - hx, py0 = pr.y - hy;
        float px1 = pr.x + hx, py1 = pr.y + hy;
        float ap = (px1 - px0) * (py1 - py0);
        float ap35 = 0.35f * ap;
        bool pa = false;
        #pragma unroll
        for (int j = 0; j < GPB; ++j) {
            float4 tb = j == 0 ? tb0 : (j == 1 ? tb1 : (j == 2 ? tb2 : tb3));
            float at = j == 0 ? at0 : (j == 1 ? at1 : (j == 2 ? at2 : at3));
            float cj = j == 0 ? c0 : (j == 1 ? c1 : (j == 2 ? c2 : c3));
            float lx = fmaxf(tb.x, px0), ly = fmaxf(tb.y, py0);
            float rx = fminf(tb.z, px1), ry = fminf(tb.w, py1);
            float iw = fmaxf(rx - lx, 0.f), ih = fmaxf(ry - ly, 0.f);
            float inter = iw * ih;
            pa = pa || (fmaf(1.35f, inter, -cj) >= ap35);   // iou >= 0.35
            float iou = inter * RCP(at + ap - inter);
            if (iou > bv[j]) { bv[j] = iou; bp[j] = p; }
        }
        u64 bal = __ballot(pa);
        if (lane == 0) wm[p >> 6] = bal;
    }
    #pragma unroll
    for (int j = 0; j < GPB; ++j) {
        u64 key = ((u64)__float_as_uint(bv[j]) << 32) | ~(unsigned)bp[j];
        #pragma unroll
        for (int o = 32; o > 0; o >>= 1) {
            u64 t = __shfl_down(key, o, 64);
            if (t > key) key = t;
        }
        if (lane == 0) s_wk[w][j] = key;
    }
    __syncthreads();
    if (tid < GPB) {
        u64 m = 0ull;
        #pragma unroll
        for (int q = 0; q < GNT / 64; ++q) { u64 t = s_wk[q][tid]; if (t > m) m = t; }
        keys[b * G + g0 + tid] = m;
    }
}

// ---- k_sel: match + select fused, one block per batch ----
constexpr int SNT = 1024;
constexpr int SNI = 17;      // ceil(16800 / 1024)
constexpr int NWV = SNT / 64;
__global__ __launch_bounds__(SNT)
void k_sel(const float2* __restrict__ cls, const float4* __restrict__ loc,
           const float* __restrict__ lmd, const float4* __restrict__ priors,
           const float* __restrict__ pack, const u64* __restrict__ keys,
           const u64* __restrict__ wmask,
           float* __restrict__ part2, float* __restrict__ out,
           int* __restrict__ done, int P, int NCH, int B) {
    const int b = blockIdx.x, tid = threadIdx.x;
    const int lane = tid & 63, w = tid >> 6;
    const float* __restrict__ pk = pack + (size_t)b * PACKF;
    const float4* __restrict__ gbox = (const float4*)pk;
    const float* __restrict__ garea = pk + 160;
    const float* __restrict__ glab = pk + 192;
    const float* __restrict__ glm  = pk + 224;

    __shared__ int      s_fg[16800];          // forced: max g per prior (67 KB)
    __shared__ unsigned s_fvb[528];           // forced-valid bit per prior
    __shared__ unsigned s_vm;
    __shared__ float    s_red[NWV][8];
    __shared__ float    s_fld[5];
    __shared__ u64      s_cw[NWV];
    __shared__ u64      s_ct;
    __shared__ float    s_rf[NWV][2];
    __shared__ float    s_ts2[2];
    __shared__ int      s_last;

    #pragma unroll
    for (int i = 0; i < SNI; ++i) {
        int idx = i * SNT + tid;
        if (idx < P) s_fg[idx] = -1;
    }
    if (tid < 528) s_fvb[tid] = 0u;
    __syncthreads();
    if (tid < GN) {                           // forced-match scatter
        u64 key = keys[b * GN + tid];
        unsigned bp = ~(unsigned)key;
        bool val = __uint_as_float((unsigned)(key >> 32)) >= 0.2f;
        u64 bal = __ballot(val);
        if (tid == 0) s_vm = (unsigned)bal;
        if ((int)bp < P) {
            atomicMax(&s_fg[bp], tid);        // largest g wins
            if (val) atomicOr(&s_fvb[bp >> 5], 1u << (bp & 31));
        }
    }
    __syncthreads();
    const bool av = s_vm != 0u;

    float a_ll = 0.f, a_lm = 0.f, a_lcp = 0.f;
    int npw = 0, np1w = 0;
    unsigned ul[SNI];
    #pragma unroll
    for (int i = 0; i < SNI; ++i) {
        int p = i * SNT + tid;
        bool act = p < P;
        float2 c = act ? cls[(size_t)b * P + p] : make_float2(0.f, 0.f);
        u64 m = 0ull;
        if (act) {
            int word = i * 16 + w;            // == p>>6, wave-uniform
            #pragma unroll
            for (int ch = 0; ch < 8; ++ch)
                m |= wmask[((size_t)b * NCH + ch) * NW64A + word];
        }
        bool thr = act && ((m >> (p & 63)) & 1ull);
        int fidx = act ? s_fg[p] : -1;
        bool fv = act && ((s_fvb[p >> 5] >> (p & 31)) & 1u);
        bool pos = act && av && (fv || thr);
        float lse = 0.f, d = 0.f;
        if (act) {
            d = c.y - c.x;
            float m0 = fmaxf(d, 0.f);
            lse = m0 + __logf(__expf(-m0) + __expf(d - m0));  // logz - c.x >= 0
        }
        ul[i] = pos ? 0u : (act ? __float_as_uint(lse) : 0u);
        if (pos) {
            npw++;
            a_lcp += lse - d;                 // logz - c.y
            float4 pr = priors[p];
            float hx = pr.z * 0.5f, hy = pr.w * 0.5f;
            float px0 = pr.x - hx, py0 = pr.y - hy;
            float px1 = pr.x + hx, py1 = pr.y + hy;
            float ap = (px1 - px0) * (py1 - py0);
            int bti2 = fidx;
            if (fidx < 0) {                   // rare: full first-g argmax
                float btv = -1.f;
                #pragma unroll 1
                for (int g = 0; g < GN; ++g) {
                    float4 tb = gbox[g];
                    float lx = fmaxf(tb.x, px0), ly = fmaxf(tb.y, py0);
                    float rx = fminf(tb.z, px1), ry = fminf(tb.w, py1);
                    float iw = fmaxf(rx - lx, 0.f), ih = fmaxf(ry - ly, 0.f);
                    float inter = iw * ih;
                    float iou = inter * RCP(garea[g] + ap - inter);
                    if (iou > btv) { btv = iou; bti2 = g; }
                }
            }
            float4 tb = gbox[bti2];
            float rw = RCP(pr.z), rh = RCP(pr.w);
            float e0 = ((tb.x + tb.z) * 0.5f - pr.x) * rw * 10.f;
            float e1 = ((tb.y + tb.w) * 0.5f - pr.y) * rh * 10.f;
            float e2 = __logf((tb.z - tb.x) * rw) * 5.f;
            float e3 = __logf((tb.w - tb.y) * rh) * 5.f;
            float4 ld = loc[(size_t)b * P + p];
            a_ll += sl1(ld.x - e0) + sl1(ld.y - e1) + sl1(ld.z - e2) + sl1(ld.w - e3);
            if (glab[bti2] > 0.f) {           // conf > 0
                np1w++;
                const float* lp = lmd + ((size_t)b * P + p) * 10;
                #pragma unroll
                for (int q = 0; q < 5; ++q) {
                    float gx = (glm[bti2 * 10 + 2 * q]     - pr.x) * rw * 10.f;
                    float gy = (glm[bti2 * 10 + 2 * q + 1] - pr.y) * rh * 10.f;
                    a_lm += sl1(lp[2 * q] - gx) + sl1(lp[2 * q + 1] - gy);
                }
            }
        }
    }
    {   // block reduce of 5 partials across 16 waves
        float a_np = (float)npw, a_np1 = (float)np1w;
        #pragma unroll
        for (int o = 32; o > 0; o >>= 1) {
            a_ll  += __shfl_down(a_ll,  o, 64);
            a_lm  += __shfl_down(a_lm,  o, 64);
            a_lcp += __shfl_down(a_lcp, o, 64);
            a_np  += __shfl_down(a_np,  o, 64);
            a_np1 += __shfl_down(a_np1, o, 64);
        }
        if (lane == 0) {
            s_red[w][0] = a_ll; s_red[w][1] = a_lm; s_red[w][2] = a_lcp;
            s_red[w][3] = a_np; s_red[w][4] = a_np1;
        }
    }
    __syncthreads();
    if (w == 0) {
        #pragma unroll
        for (int j = 0; j < 5; ++j) {
            float v = (lane < NWV) ? s_red[lane][j] : 0.f;
            #pragma unroll
            for (int o = 8; o > 0; o >>= 1) v += __shfl_down(v, o, 64);
            if (lane == 0) s_fld[j] = v;
        }
    }
    __syncthreads();
    const float t_ll = s_fld[0], t_lm = s_fld[1], t_lcp = s_fld[2];
    const float t_np = s_fld[3], t_np1 = s_fld[4];
    int k = (int)(t_np + 0.5f) * 7;
    if (k > P - 1) k = P - 1;

    float topk = 0.f;
    if (k > 0) {
        unsigned lo = 0u, hi = 0x7f800000u;   // finite non-negative values
        while (lo < hi) {                     // ~15 rounds (4-way)
            unsigned span = hi - lo;
            unsigned m1 = lo + ((span + 3) >> 2);
            unsigned m2 = lo + ((span + 1) >> 1);
            unsigned m3 = hi - (span >> 2);
            int c1 = 0, c2 = 0, c3 = 0;
            #pragma unroll
            for (int i = 0; i < SNI; ++i) {
                unsigned u = ul[i];
                c1 += u >= m1 ? 1 : 0;
                c2 += u >= m2 ? 1 : 0;
                c3 += u >= m3 ? 1 : 0;
            }
            u64 pkk = (u64)c1 | ((u64)c2 << 20) | ((u64)c3 << 40);
            #pragma unroll
            for (int o = 32; o > 0; o >>= 1) pkk += __shfl_down(pkk, o, 64);
            if (lane == 0) s_cw[w] = pkk;
            __syncthreads();
            if (w == 0) {
                u64 t = (lane < NWV) ? s_cw[lane] : 0ull;
                #pragma unroll
                for (int o = 8; o > 0; o >>= 1) t += __shfl_down(t, o, 64);
                if (lane == 0) s_ct = t;
            }
            __syncthreads();
            u64 t = s_ct;
            int C1 = (int)(t & 0xFFFFFu);
            int C2 = (int)((t >> 20) & 0xFFFFFu);
            int C3 = (int)((t >> 40) & 0xFFFFFu);
            if      (C3 >= k) lo = m3;
            else if (C2 >= k) { lo = m2; hi = m3 - 1; }
            else if (C1 >= k) { lo = m1; hi = m2 - 1; }
            else hi = m1 - 1;
        }
        float fT = __uint_as_float(lo);       // exact k-th largest
        float s = 0.f, cf = 0.f;
        #pragma unroll
        for (int i = 0; i < SNI; ++i)
            if (ul[i] > lo) { s += __uint_as_float(ul[i]); cf += 1.f; }
        #pragma unroll
        for (int o = 32; o > 0; o >>= 1) {
            s  += __shfl_down(s, o, 64);
            cf += __shfl_down(cf, o, 64);
        }
        if (lane == 0) { s_rf[w][0] = s; s_rf[w][1] = cf; }
        __syncthreads();
        if (w == 0) {
            float a = (lane < NWV) ? s_rf[lane][0] : 0.f;
            float bb = (lane < NWV) ? s_rf[lane][1] : 0.f;
            #pragma unroll
            for (int o = 8; o > 0; o >>= 1) {
                a  += __shfl_down(a, o, 64);
                bb += __shfl_down(bb, o, 64);
            }
            if (lane == 0) { s_ts2[0] = a; s_ts2[1] = bb; }
        }
        __syncthreads();
        topk = s_ts2[0] + ((float)k - s_ts2[1]) * fT;  // ties add (k-cnt)*T
    }
    if (tid == 0) {
        float* pp = part2 + b * 8;
        pp[0] = t_ll; pp[1] = t_lm; pp[2] = t_lcp;
        pp[3] = topk; pp[4] = t_np; pp[5] = t_np1;
        __threadfence();
        int old = atomicAdd(done, 1);
        s_last = (old == B - 1) ? 1 : 0;
    }
    __syncthreads();
    if (s_last && w == 0) {                   // last block folds all rows
        __threadfence();
        volatile float* vp = part2;
        float ll = 0.f, lm = 0.f, lc = 0.f, tk = 0.f, np = 0.f, np1 = 0.f;
        for (int bb = lane; bb < B; bb += 64) {
            ll  += vp[bb * 8 + 0];
            lm  += vp[bb * 8 + 1];
            lc  += vp[bb * 8 + 2];
            tk  += vp[bb * 8 + 3];
            np  += vp[bb * 8 + 4];
            np1 += vp[bb * 8 + 5];
        }
        #pragma unroll
        for (int o = 32; o > 0; o >>= 1) {
            ll  += __shfl_down(ll,  o, 64);
            lm  += __shfl_down(lm,  o, 64);
            lc  += __shfl_down(lc,  o, 64);
            tk  += __shfl_down(tk,  o, 64);
            np  += __shfl_down(np,  o, 64);
            np1 += __shfl_down(np1, o, 64);
        }
        if (lane == 0) {
            float N = fmaxf(np, 1.f), N1 = fmaxf(np1, 1.f);
            out[0] = ll / N;
            out[1] = (lc + tk) / N;
            out[2] = lm / N1;
        }
    }
}

extern "C" void kernel_launch(void* const* d_in, const int* in_sizes, int n_in,
                              void* d_out, int out_size, void* d_ws, size_t ws_size,
                              hipStream_t stream) {
    const float2* cls    = (const float2*)d_in[0];
    const float4* loc    = (const float4*)d_in[1];
    const float* lmd     = (const float*)d_in[2];
    const float4* priors = (const float4*)d_in[3];
    const float* targets = (const float*)d_in[4];
    int P = in_sizes[3] / 4;            // 16800
    int B = (in_sizes[1] / 4) / P;      // 64
    int G = in_sizes[4] / (15 * B);     // 32
    int NCH = (G + GPB - 1) / GPB;      // 8 chunks

    size_t off = 0;
    u64* keys    = (u64*)d_ws;                     off += (size_t)B * G * 8;
    u64* wmask   = (u64*)((char*)d_ws + off);      off += (size_t)B * NCH * NW64A * 8;
    float* pack  = (float*)((char*)d_ws + off);    off += (size_t)B * PACKF * 4;
    float* part2 = (float*)((char*)d_ws + off);    off += (size_t)B * 8 * 4;
    int* done    = (int*)((char*)d_ws + off);

    dim3 ggt(NCH, B);
    k_gt<<<ggt, GNT, 0, stream>>>(priors, targets, keys, pack, wmask, done, P, G, NCH);
    k_sel<<<B, SNT, 0, stream>>>(cls, loc, lmd, priors, pack, keys, wmask,
                                 part2, (float*)d_out, done, P, NCH, B);
}

// Round 17
// 91.046 us; speedup vs baseline: 4.1439x; 1.9609x over previous
//
#include <hip/hip_runtime.h>
#include <hip/hip_bf16.h>
#include <math.h>

// MultiBoxLoss: B=64, P=16800, G=32, C=2. 3-kernel pipeline (r13 + GPB=8):
// k_gt     (4x64 blocks, 1024 thr): per-gt best-prior argmax (8 gts/block) +
//          per-prior threshold bitmask -> keys + wmask; packs gt table.
// k_match  (66x64 blocks, 256 thr): threshold = 4 uniform u64 loads + OR;
//          forced-match via LDS scatter; rare positives full argmax;
//          writes bc + 5 block partials.
// k_select (64 blocks, 1024 thr): 4-way bisection exact k-th largest over
//          register-resident conf-losses; done-counter last-block fold.

#define RCP(x) __builtin_amdgcn_rcpf(x)
typedef unsigned long long u64;

constexpr int GN = 32;
constexpr int PACKF = 576;
constexpr int NW64A = 264;   // mask words per (batch, chunk)

__device__ __forceinline__ float sl1(float x) {
    float a = fabsf(x);
    return a < 1.f ? 0.5f * a * a : a - 0.5f;
}

// ---- k_gt: argmax + threshold bitmask + gt pack (GPB=8) ----
constexpr int GPB = 8;       // gts per chunk
constexpr int GNT = 1024;
__global__ __launch_bounds__(GNT)
void k_gt(const float4* __restrict__ priors, const float* __restrict__ targets,
          u64* __restrict__ keys, float* __restrict__ pack, u64* __restrict__ wmask,
          int* __restrict__ done, int P, int G, int NCH) {
    const int b = blockIdx.y, cx = blockIdx.x, g0 = cx * GPB, tid = threadIdx.x;
    const int lane = tid & 63, w = tid >> 6;
    if (cx == 0 && b == 0 && tid == 0) *done = 0;
    __shared__ float4 s_box[GPB];
    __shared__ float  s_at[GPB];
    __shared__ u64 s_wk[GNT / 64][GPB];
    if (tid < GPB) {
        const float* t = targets + ((size_t)b * G + g0 + tid) * 15;
        float4 v = make_float4(t[0], t[1], t[2], t[3]);
        float at = (v.z - v.x) * (v.w - v.y);
        s_box[tid] = v;
        s_at[tid] = at;
        float* pkw = pack + (size_t)b * PACKF;
        ((float4*)pkw)[g0 + tid] = v;
        pkw[128 + g0 + tid] = 0.35f * at;
        pkw[160 + g0 + tid] = at;
        pkw[192 + g0 + tid] = t[14];
    }
    {
        int q = tid - GPB;
        if (q >= 0 && q < GPB * 10) {
            int gg = g0 + q / 10, j = q % 10;
            pack[(size_t)b * PACKF + 224 + gg * 10 + j] =
                targets[((size_t)b * G + gg) * 15 + 4 + j];
        }
    }
    __syncthreads();
    float4 tb[GPB]; float at_[GPB], c35_[GPB];
    #pragma unroll
    for (int j = 0; j < GPB; ++j) {
        tb[j] = s_box[j]; at_[j] = s_at[j]; c35_[j] = 0.35f * s_at[j];
    }
    float bv[GPB]; int bp[GPB];
    #pragma unroll
    for (int j = 0; j < GPB; ++j) { bv[j] = -1.f; bp[j] = 0; }

    u64* __restrict__ wm = wmask + ((size_t)b * NCH + cx) * NW64A;

    for (int p = tid; p < P; p += GNT) {     // ascending p: '>' keeps smallest p
        float4 pr = priors[p];
        float hx = pr.z * 0.5f, hy = pr.w * 0.5f;
        float px0 = pr.x - hx, py0 = pr.y - hy;
        float px1 = pr.x + hx, py1 = pr.y + hy;
        float ap = (px1 - px0) * (py1 - py0);
        float ap35 = 0.35f * ap;
        bool pa = false;
        #pragma unroll
        for (int j = 0; j < GPB; ++j) {
            float lx = fmaxf(tb[j].x, px0), ly = fmaxf(tb[j].y, py0);
            float rx = fminf(tb[j].z, px1), ry = fminf(tb[j].w, py1);
            float iw = fmaxf(rx - lx, 0.f), ih = fmaxf(ry - ly, 0.f);
            float inter = iw * ih;
            pa = pa || (fmaf(1.35f, inter, -c35_[j]) >= ap35);   // iou >= 0.35
            float iou = inter * RCP(at_[j] + ap - inter);
            if (iou > bv[j]) { bv[j] = iou; bp[j] = p; }
        }
        u64 bal = __ballot(pa);
        if (lane == 0) wm[p >> 6] = bal;
    }
    #pragma unroll
    for (int j = 0; j < GPB; ++j) {
        u64 key = ((u64)__float_as_uint(bv[j]) << 32) | ~(unsigned)bp[j];
        #pragma unroll
        for (int o = 32; o > 0; o >>= 1) {
            u64 t = __shfl_down(key, o, 64);
            if (t > key) key = t;
        }
        if (lane == 0) s_wk[w][j] = key;
    }
    __syncthreads();
    if (tid < GPB) {
        u64 m = 0ull;
        #pragma unroll
        for (int q = 0; q < GNT / 64; ++q) { u64 t = s_wk[q][tid]; if (t > m) m = t; }
        keys[b * G + g0 + tid] = m;
    }
}

// ---- k_match: no g-loop; threshold from wmask (4 chunks) ----
__global__ __launch_bounds__(256)
void k_match(const float2* __restrict__ cls, const float4* __restrict__ loc,
             const float* __restrict__ lmd, const float4* __restrict__ priors,
             const float* __restrict__ pack, const u64* __restrict__ keys,
             const u64* __restrict__ wmask,
             float* __restrict__ bc, float* __restrict__ part,
             int P, int NB, int NCH) {
    const int b = blockIdx.y, bx = blockIdx.x, tid = threadIdx.x;
    const int lane = tid & 63, w = tid >> 6;
    const float* __restrict__ pk = pack + (size_t)b * PACKF;
    const float4* __restrict__ gbox = (const float4*)pk;
    const float* __restrict__ garea = pk + 160;
    const float* __restrict__ glab = pk + 192;
    const float* __restrict__ glm  = pk + 224;

    __shared__ int s_fg[256];
    __shared__ int s_fv[256];
    __shared__ unsigned s_vm;
    __shared__ float s_red[4][8];

    s_fg[tid] = -1; s_fv[tid] = 0;
    __syncthreads();
    if (tid < GN) {                                   // forced-match scatter
        u64 key = keys[b * GN + tid];
        unsigned bp = ~(unsigned)key;
        bool val = __uint_as_float((unsigned)(key >> 32)) >= 0.2f;
        u64 bal = __ballot(val);
        if (tid == 0) s_vm = (unsigned)bal;
        int local = (int)bp - bx * 256;
        if (local >= 0 && local < 256) {
            atomicMax(&s_fg[local], tid);
            if (val) atomicOr(&s_fv[local], 1);
        }
    }

    int p = bx * 256 + tid;
    const bool act = p < P;
    float2 c = act ? cls[(size_t)b * P + p] : make_float2(0.f, 0.f);

    // threshold: OR the 4 chunk masks for this wave's 64-prior word
    const int word = bx * 4 + w;
    u64 m = 0ull;
    #pragma unroll
    for (int ch = 0; ch < 4; ++ch)
        m |= wmask[((size_t)b * NCH + ch) * NW64A + word];
    __syncthreads();                                  // covers scatter
    const bool av = s_vm != 0u;

    bool thr = act && ((m >> lane) & 1ull);
    int fidx = s_fg[tid];
    bool fv = s_fv[tid] != 0;
    bool pos = act && av && (fv || thr);

    float lse = 0.f, d = 0.f;
    if (act) {
        d = c.y - c.x;
        float m0 = fmaxf(d, 0.f);
        lse = m0 + __logf(__expf(-m0) + __expf(d - m0));   // logz - c.x >= 0
        bc[(size_t)b * P + p] = pos ? 0.f : lse;
    }

    float a_ll = 0.f, a_lm = 0.f, a_lcp = 0.f;
    bool posl = false;
    if (pos) {                                        // rare path only
        a_lcp = lse - d;
        float4 pr = priors[p];
        float hx = pr.z * 0.5f, hy = pr.w * 0.5f;
        float px0 = pr.x - hx, py0 = pr.y - hy;
        float px1 = pr.x + hx, py1 = pr.y + hy;
        float ap = (px1 - px0) * (py1 - py0);
        int bti2 = fidx;
        if (fidx < 0) {                               // full first-g argmax
            float btv = -1.f;
            #pragma unroll 1
            for (int g = 0; g < GN; ++g) {
                float4 tb = gbox[g];
                float lx = fmaxf(tb.x, px0), ly = fmaxf(tb.y, py0);
                float rx = fminf(tb.z, px1), ry = fminf(tb.w, py1);
                float iw = fmaxf(rx - lx, 0.f), ih = fmaxf(ry - ly, 0.f);
                float inter = iw * ih;
                float iou = inter * RCP(garea[g] + ap - inter);
                if (iou > btv) { btv = iou; bti2 = g; }
            }
        }
        float4 tb = gbox[bti2];
        float rw = RCP(pr.z), rh = RCP(pr.w);
        float e0 = ((tb.x + tb.z) * 0.5f - pr.x) * rw * 10.f;
        float e1 = ((tb.y + tb.w) * 0.5f - pr.y) * rh * 10.f;
        float e2 = __logf((tb.z - tb.x) * rw) * 5.f;
        float e3 = __logf((tb.w - tb.y) * rh) * 5.f;
        float4 ld = loc[(size_t)b * P + p];
        a_ll = sl1(ld.x - e0) + sl1(ld.y - e1) + sl1(ld.z - e2) + sl1(ld.w - e3);
        if (glab[bti2] > 0.f) {
            posl = true;
            const float* lp = lmd + ((size_t)b * P + p) * 10;
            #pragma unroll
            for (int q = 0; q < 5; ++q) {
                float gx = (glm[bti2 * 10 + 2 * q]     - pr.x) * rw * 10.f;
                float gy = (glm[bti2 * 10 + 2 * q + 1] - pr.y) * rh * 10.f;
                a_lm += sl1(lp[2 * q] - gx) + sl1(lp[2 * q + 1] - gy);
            }
        }
    }

    u64 bpos = __ballot(pos);
    int npw  = __popcll(bpos);
    int np1w = __popcll(__ballot(posl));
    if (bpos) {                                       // skip shuffles for all-neg waves
        #pragma unroll
        for (int o = 32; o > 0; o >>= 1) {
            a_ll  += __shfl_down(a_ll,  o, 64);
            a_lm  += __shfl_down(a_lm,  o, 64);
            a_lcp += __shfl_down(a_lcp, o, 64);
        }
    }
    if (lane == 0) {
        s_red[w][0] = a_ll; s_red[w][1] = a_lm; s_red[w][2] = a_lcp;
        s_red[w][3] = (float)npw; s_red[w][4] = (float)np1w;
    }
    __syncthreads();
    if (tid == 0) {
        float* pp = part + ((size_t)b * NB + bx) * 8;
        #pragma unroll
        for (int j = 0; j < 5; ++j)
            pp[j] = s_red[0][j] + s_red[1][j] + s_red[2][j] + s_red[3][j];
    }
}

// ---- k_select: exact top-k via 4-way bisection; last block folds ----
constexpr int KNT = 1024;
constexpr int KNI = 17;      // ceil(16800 / 1024)
__global__ __launch_bounds__(KNT)
void k_select(const float* __restrict__ bc, const float* __restrict__ part,
              float* __restrict__ part2, float* __restrict__ out,
              int* __restrict__ done, int P, int NB, int B) {
    const int b = blockIdx.x, tid = threadIdx.x;
    const int lane = tid & 63, w = tid >> 6;
    __shared__ float s_r[5];
    __shared__ u64   s_cw[16];
    __shared__ u64   s_ct;
    __shared__ float s_rf[16][2];
    __shared__ float s_ts2[2];
    __shared__ int   s_last;

    unsigned ul[KNI];
    #pragma unroll
    for (int i = 0; i < KNI; ++i) {
        int idx = i * KNT + tid;
        ul[i] = idx < P ? __float_as_uint(bc[(size_t)b * P + idx]) : 0u;
    }
    if (w < 5) {                                      // wave j reduces part field j
        float s = 0.f;
        for (int bx = lane; bx < NB; bx += 64) s += part[((size_t)b * NB + bx) * 8 + w];
        #pragma unroll
        for (int o = 32; o > 0; o >>= 1) s += __shfl_down(s, o, 64);
        if (lane == 0) s_r[w] = s;
    }
    __syncthreads();
    const float t_ll = s_r[0], t_lm = s_r[1], t_lcp = s_r[2];
    const float t_np = s_r[3], t_np1 = s_r[4];
    int k = (int)(t_np + 0.5f) * 7;
    if (k > P - 1) k = P - 1;

    float topk = 0.f;
    if (k > 0) {
        unsigned lo = 0u, hi = 0x7f800000u;           // finite non-negative values
        while (lo < hi) {                             // ~15 rounds (4-way)
            unsigned span = hi - lo;
            unsigned m1 = lo + ((span + 3) >> 2);
            unsigned m2 = lo + ((span + 1) >> 1);
            unsigned m3 = hi - (span >> 2);
            int c1 = 0, c2 = 0, c3 = 0;
            #pragma unroll
            for (int i = 0; i < KNI; ++i) {
                unsigned u = ul[i];
                c1 += u >= m1 ? 1 : 0;
                c2 += u >= m2 ? 1 : 0;
                c3 += u >= m3 ? 1 : 0;
            }
            u64 pkk = (u64)c1 | ((u64)c2 << 20) | ((u64)c3 << 40);
            #pragma unroll
            for (int o = 32; o > 0; o >>= 1) pkk += __shfl_down(pkk, o, 64);
            if (lane == 0) s_cw[w] = pkk;
            __syncthreads();
            if (w == 0) {                             // wave-0 shuffle fold
                u64 t = (lane < 16) ? s_cw[lane] : 0ull;
                #pragma unroll
                for (int o = 8; o > 0; o >>= 1) t += __shfl_down(t, o, 64);
                if (lane == 0) s_ct = t;
            }
            __syncthreads();
            u64 t = s_ct;
            int C1 = (int)(t & 0xFFFFFu);
            int C2 = (int)((t >> 20) & 0xFFFFFu);
            int C3 = (int)((t >> 40) & 0xFFFFFu);
            if      (C3 >= k) lo = m3;
            else if (C2 >= k) { lo = m2; hi = m3 - 1; }
            else if (C1 >= k) { lo = m1; hi = m2 - 1; }
            else hi = m1 - 1;
        }
        float fT = __uint_as_float(lo);               // exact k-th largest
        float s = 0.f, cf = 0.f;
        #pragma unroll
        for (int i = 0; i < KNI; ++i)
            if (ul[i] > lo) { s += __uint_as_float(ul[i]); cf += 1.f; }
        #pragma unroll
        for (int o = 32; o > 0; o >>= 1) {
            s  += __shfl_down(s, o, 64);
            cf += __shfl_down(cf, o, 64);
        }
        if (lane == 0) { s_rf[w][0] = s; s_rf[w][1] = cf; }
        __syncthreads();
        if (w == 0) {
            float a = (lane < 16) ? s_rf[lane][0] : 0.f;
            float bb = (lane < 16) ? s_rf[lane][1] : 0.f;
            #pragma unroll
            for (int o = 8; o > 0; o >>= 1) {
                a  += __shfl_down(a, o, 64);
                bb += __shfl_down(bb, o, 64);
            }
            if (lane == 0) { s_ts2[0] = a; s_ts2[1] = bb; }
        }
        __syncthreads();
        topk = s_ts2[0] + ((float)k - s_ts2[1]) * fT; // ties add (k-cnt)*T
    }
    if (tid == 0) {
        float* pp = part2 + b * 8;
        pp[0] = t_ll; pp[1] = t_lm; pp[2] = t_lcp;
        pp[3] = topk; pp[4] = t_np; pp[5] = t_np1;
        __threadfence();
        int old = atomicAdd(done, 1);
        s_last = (old == B - 1) ? 1 : 0;
    }
    __syncthreads();
    if (s_last && w == 0) {                           // last block folds all rows
        __threadfence();
        volatile float* vp = part2;
        float ll = 0.f, lm = 0.f, lc = 0.f, tk = 0.f, np = 0.f, np1 = 0.f;
        for (int bb = lane; bb < B; bb += 64) {
            ll  += vp[bb * 8 + 0];
            lm  += vp[bb * 8 + 1];
            lc  += vp[bb * 8 + 2];
            tk  += vp[bb * 8 + 3];
            np  += vp[bb * 8 + 4];
            np1 += vp[bb * 8 + 5];
        }
        #pragma unroll
        for (int o = 32; o > 0; o >>= 1) {
            ll  += __shfl_down(ll,  o, 64);
            lm  += __shfl_down(lm,  o, 64);
            lc  += __shfl_down(lc,  o, 64);
            tk  += __shfl_down(tk,  o, 64);
            np  += __shfl_down(np,  o, 64);
            np1 += __shfl_down(np1, o, 64);
        }
        if (lane == 0) {
            float N = fmaxf(np, 1.f), N1 = fmaxf(np1, 1.f);
            out[0] = ll / N;
            out[1] = (lc + tk) / N;
            out[2] = lm / N1;
        }
    }
}

extern "C" void kernel_launch(void* const* d_in, const int* in_sizes, int n_in,
                              void* d_out, int out_size, void* d_ws, size_t ws_size,
                              hipStream_t stream) {
    const float2* cls    = (const float2*)d_in[0];
    const float4* loc    = (const float4*)d_in[1];
    const float* lmd     = (const float*)d_in[2];
    const float4* priors = (const float4*)d_in[3];
    const float* targets = (const float*)d_in[4];
    int P = in_sizes[3] / 4;            // 16800
    int B = (in_sizes[1] / 4) / P;      // 64
    int G = in_sizes[4] / (15 * B);     // 32
    int NB = (P + 255) / 256;           // 66
    int NCH = (G + GPB - 1) / GPB;      // 4 chunks

    size_t off = 0;
    u64* keys    = (u64*)d_ws;                     off += (size_t)B * G * 8;
    u64* wmask   = (u64*)((char*)d_ws + off);      off += (size_t)B * NCH * NW64A * 8;
    float* pack  = (float*)((char*)d_ws + off);    off += (size_t)B * PACKF * 4;
    float* part  = (float*)((char*)d_ws + off);    off += (size_t)B * NB * 8 * 4;
    float* part2 = (float*)((char*)d_ws + off);    off += (size_t)B * 8 * 4;
    int* done    = (int*)((char*)d_ws + off);      off += 256;
    off = (off + 255) & ~(size_t)255;
    float* bc    = (float*)((char*)d_ws + off);

    dim3 ggt(NCH, B);
    k_gt<<<ggt, GNT, 0, stream>>>(priors, targets, keys, pack, wmask, done, P, G, NCH);
    dim3 gm(NB, B);
    k_match<<<gm, 256, 0, stream>>>(cls, loc, lmd, priors, pack, keys, wmask,
                                    bc, part, P, NB, NCH);
    k_select<<<B, KNT, 0, stream>>>(bc, part, part2, (float*)d_out, done, P, NB, B);
}